// Round 3
// baseline (64.116 us; speedup 1.0000x reference)
//
#include <hip/hip_runtime.h>

#define IGNORE_LABEL 255

constexpr int B      = 8;
constexpr int BANDS  = 31;
constexpr int H      = 512;
constexpr int W      = 512;
constexpr int NMAT   = 16;
constexpr int HW     = H * W;                     // 262144 (2^18)
constexpr long TOTAL_PIX = (long)B * HW;          // 2,097,152
constexpr int  PPT       = 8;                     // pixels per thread
constexpr int  NBLOCKS   = (int)(TOTAL_PIX / (PPT * 256));  // 1024 (exact)

typedef float  f32x4 __attribute__((ext_vector_type(4)));
typedef int    i32x4 __attribute__((ext_vector_type(4)));

__global__ __launch_bounds__(256) void sad_main_kernel(
    const float* __restrict__ input,      // [B][BANDS][H][W]
    const int*   __restrict__ target,     // [B][1][H][W]
    const float* __restrict__ materials,  // [NMAT][BANDS]
    float*       __restrict__ part)       // [NBLOCKS]
{
    __shared__ float s_mat[NMAT][BANDS];
    __shared__ float s_tn2[NMAT];
    __shared__ float s_part[4];

    const int tid = threadIdx.x;

    // Addressing + target loads issued BEFORE the staging barrier so the
    // 32 B/lane target read overlaps materials staging.
    const long pix = ((long)blockIdx.x * blockDim.x + tid) * PPT;
    const int  b   = (int)(pix >> 18);            // pix / HW (HW = 2^18)
    const int  off = (int)(pix & (HW - 1));

    const int* tp = &target[(long)b * HW + off];
    const i32x4 code_lo = __builtin_nontemporal_load((const i32x4*)tp);
    const i32x4 code_hi = __builtin_nontemporal_load((const i32x4*)(tp + 4));
    const float* ip = input + (long)b * BANDS * HW + off;

    // Stage materials into LDS (496 floats) + per-material ||t||^2.
    for (int i = tid; i < NMAT * BANDS; i += blockDim.x)
        s_mat[i / BANDS][i % BANDS] = materials[i];
    __syncthreads();
    if (tid < NMAT) {
        float s = 0.f;
        #pragma unroll
        for (int c = 0; c < BANDS; ++c) {
            float m = s_mat[tid][c];
            s = fmaf(m, m, s);
        }
        s_tn2[tid] = s;
    }
    __syncthreads();

    int codes[PPT] = { code_lo.x, code_lo.y, code_lo.z, code_lo.w,
                       code_hi.x, code_hi.y, code_hi.z, code_hi.w };
    int safec[PPT];
    #pragma unroll
    for (int j = 0; j < PPT; ++j) {
        int c = (codes[j] == IGNORE_LABEL) ? 0 : codes[j];
        safec[j] = (c < 0) ? 0 : ((c >= NMAT) ? 0 : c);  // memory-safety clamp
    }

    float dot[PPT];
    float xn [PPT];
    #pragma unroll
    for (int j = 0; j < PPT; ++j) { dot[j] = 0.f; xn[j] = 0.f; }

    #pragma unroll
    for (int c = 0; c < BANDS; ++c) {
        const float* bp = ip + (long)c * HW;
        const f32x4 v0 = __builtin_nontemporal_load((const f32x4*)bp);
        const f32x4 v1 = __builtin_nontemporal_load((const f32x4*)(bp + 4));
        #pragma unroll
        for (int j = 0; j < 4; ++j) {
            const float m0 = s_mat[safec[j]][c];
            const float m1 = s_mat[safec[j + 4]][c];
            dot[j]     = fmaf(v0[j], m0, dot[j]);
            xn [j]     = fmaf(v0[j], v0[j], xn[j]);
            dot[j + 4] = fmaf(v1[j], m1, dot[j + 4]);
            xn [j + 4] = fmaf(v1[j], v1[j], xn[j + 4]);
        }
    }

    float acc = 0.f;
    #pragma unroll
    for (int j = 0; j < PPT; ++j) {
        if (codes[j] != IGNORE_LABEL) {
            const float denom = sqrtf(xn[j] * s_tn2[safec[j]]);
            float cosv = dot[j] / denom;
            cosv = fminf(fmaxf(cosv, -1.f + 1e-7f), 1.f - 1e-7f);
            acc += acosf(cosv);
        }
    }

    // Wave-64 reduction, then per-block partial to workspace (no atomics).
    #pragma unroll
    for (int o = 32; o > 0; o >>= 1)
        acc += __shfl_down(acc, o, 64);

    const int wid = tid >> 6;
    if ((tid & 63) == 0) s_part[wid] = acc;
    __syncthreads();
    if (tid == 0) {
        const float s = s_part[0] + s_part[1] + s_part[2] + s_part[3];
        __builtin_nontemporal_store(s, &part[blockIdx.x]);
    }
}

__global__ __launch_bounds__(256) void sad_reduce_kernel(
    const float* __restrict__ part,  // [NBLOCKS]
    float*       __restrict__ out)   // [1]
{
    __shared__ float s_part[4];
    const int tid = threadIdx.x;

    float acc = 0.f;
    #pragma unroll
    for (int i = 0; i < NBLOCKS / 256; ++i)   // 4 each
        acc += part[i * 256 + tid];

    #pragma unroll
    for (int o = 32; o > 0; o >>= 1)
        acc += __shfl_down(acc, o, 64);

    const int wid = tid >> 6;
    if ((tid & 63) == 0) s_part[wid] = acc;
    __syncthreads();
    if (tid == 0)
        out[0] = s_part[0] + s_part[1] + s_part[2] + s_part[3];
}

extern "C" void kernel_launch(void* const* d_in, const int* in_sizes, int n_in,
                              void* d_out, int out_size, void* d_ws, size_t ws_size,
                              hipStream_t stream) {
    const float* input     = (const float*)d_in[0];
    const int*   target    = (const int*)  d_in[1];
    const float* materials = (const float*)d_in[2];
    float*       out       = (float*)d_out;
    float*       part      = (float*)d_ws;   // 1024 floats = 4 KB scratch

    sad_main_kernel<<<NBLOCKS, 256, 0, stream>>>(input, target, materials, part);
    sad_reduce_kernel<<<1, 256, 0, stream>>>(part, out);
}

// Round 4
// 62.844 us; speedup vs baseline: 1.0203x; 1.0203x over previous
//
#include <hip/hip_runtime.h>

#define IGNORE_LABEL 255

constexpr int B      = 8;
constexpr int BANDS  = 31;
constexpr int H      = 512;
constexpr int W      = 512;
constexpr int NMAT   = 16;
constexpr int HW     = H * W;                     // 262144 (2^18)
constexpr long TOTAL_PIX = (long)B * HW;          // 2,097,152
constexpr int  BLOCK_PIX = 2048;                  // 256 thr × 8 px
constexpr int  NBLOCKS   = (int)(TOTAL_PIX / BLOCK_PIX);  // 1024 (exact)

typedef float  f32x4 __attribute__((ext_vector_type(4)));
typedef int    i32x4 __attribute__((ext_vector_type(4)));

__global__ __launch_bounds__(256) void sad_main_kernel(
    const float* __restrict__ input,      // [B][BANDS][H][W]
    const int*   __restrict__ target,     // [B][1][H][W]
    const float* __restrict__ materials,  // [NMAT][BANDS]
    float*       __restrict__ part)       // [NBLOCKS]
{
    __shared__ float s_mat[NMAT][BANDS];
    __shared__ float s_tn2[NMAT];
    __shared__ float s_part[4];

    const int tid = threadIdx.x;

    // Two wave-contiguous pixel groups per thread: every load instruction
    // covers a fully-contiguous 1 KiB wave segment (unlike R3's 32B-strided
    // pattern which doubled per-instruction cache-line transactions).
    const long base = (long)blockIdx.x * BLOCK_PIX;
    const int  b    = (int)(base >> 18);          // base / HW (block never straddles b)
    const int  off0 = (int)(base & (HW - 1)) + 4 * tid;
    const int  off1 = off0 + 1024;

    const int* tp0 = &target[(long)b * HW + off0];
    const int* tp1 = &target[(long)b * HW + off1];
    const i32x4 code_lo = __builtin_nontemporal_load((const i32x4*)tp0);
    const i32x4 code_hi = __builtin_nontemporal_load((const i32x4*)tp1);
    const float* ip0 = input + (long)b * BANDS * HW + off0;
    const float* ip1 = input + (long)b * BANDS * HW + off1;

    // Stage materials into LDS (496 floats) + per-material ||t||^2.
    for (int i = tid; i < NMAT * BANDS; i += blockDim.x)
        s_mat[i / BANDS][i % BANDS] = materials[i];
    __syncthreads();
    if (tid < NMAT) {
        float s = 0.f;
        #pragma unroll
        for (int c = 0; c < BANDS; ++c) {
            float m = s_mat[tid][c];
            s = fmaf(m, m, s);
        }
        s_tn2[tid] = s;
    }
    __syncthreads();

    int codes[8] = { code_lo.x, code_lo.y, code_lo.z, code_lo.w,
                     code_hi.x, code_hi.y, code_hi.z, code_hi.w };
    int safec[8];
    #pragma unroll
    for (int j = 0; j < 8; ++j) {
        int c = (codes[j] == IGNORE_LABEL) ? 0 : codes[j];
        safec[j] = (c < 0) ? 0 : ((c >= NMAT) ? 0 : c);  // memory-safety clamp
    }

    float dot[8];
    float xn [8];
    #pragma unroll
    for (int j = 0; j < 8; ++j) { dot[j] = 0.f; xn[j] = 0.f; }

    #pragma unroll
    for (int c = 0; c < BANDS; ++c) {
        const f32x4 v0 = __builtin_nontemporal_load((const f32x4*)&ip0[(long)c * HW]);
        const f32x4 v1 = __builtin_nontemporal_load((const f32x4*)&ip1[(long)c * HW]);
        #pragma unroll
        for (int j = 0; j < 4; ++j) {
            const float m0 = s_mat[safec[j]][c];
            const float m1 = s_mat[safec[j + 4]][c];
            dot[j]     = fmaf(v0[j], m0, dot[j]);
            xn [j]     = fmaf(v0[j], v0[j], xn[j]);
            dot[j + 4] = fmaf(v1[j], m1, dot[j + 4]);
            xn [j + 4] = fmaf(v1[j], v1[j], xn[j + 4]);
        }
    }

    float acc = 0.f;
    #pragma unroll
    for (int j = 0; j < 8; ++j) {
        if (codes[j] != IGNORE_LABEL) {
            const float denom = sqrtf(xn[j] * s_tn2[safec[j]]);
            float cosv = dot[j] / denom;
            cosv = fminf(fmaxf(cosv, -1.f + 1e-7f), 1.f - 1e-7f);
            acc += acosf(cosv);
        }
    }

    // Wave-64 reduction, then per-block partial to workspace (no atomics).
    #pragma unroll
    for (int o = 32; o > 0; o >>= 1)
        acc += __shfl_down(acc, o, 64);

    const int wid = tid >> 6;
    if ((tid & 63) == 0) s_part[wid] = acc;
    __syncthreads();
    if (tid == 0) {
        const float s = s_part[0] + s_part[1] + s_part[2] + s_part[3];
        __builtin_nontemporal_store(s, &part[blockIdx.x]);
    }
}

__global__ __launch_bounds__(256) void sad_reduce_kernel(
    const float* __restrict__ part,  // [NBLOCKS]
    float*       __restrict__ out)   // [1]
{
    __shared__ float s_part[4];
    const int tid = threadIdx.x;

    float acc = 0.f;
    #pragma unroll
    for (int i = 0; i < NBLOCKS / 256; ++i)   // 4 each
        acc += part[i * 256 + tid];

    #pragma unroll
    for (int o = 32; o > 0; o >>= 1)
        acc += __shfl_down(acc, o, 64);

    const int wid = tid >> 6;
    if ((tid & 63) == 0) s_part[wid] = acc;
    __syncthreads();
    if (tid == 0)
        out[0] = s_part[0] + s_part[1] + s_part[2] + s_part[3];
}

extern "C" void kernel_launch(void* const* d_in, const int* in_sizes, int n_in,
                              void* d_out, int out_size, void* d_ws, size_t ws_size,
                              hipStream_t stream) {
    const float* input     = (const float*)d_in[0];
    const int*   target    = (const int*)  d_in[1];
    const float* materials = (const float*)d_in[2];
    float*       out       = (float*)d_out;
    float*       part      = (float*)d_ws;   // 1024 floats = 4 KB scratch

    sad_main_kernel<<<NBLOCKS, 256, 0, stream>>>(input, target, materials, part);
    sad_reduce_kernel<<<1, 256, 0, stream>>>(part, out);
}

// Round 5
// 48.025 us; speedup vs baseline: 1.3351x; 1.3086x over previous
//
#include <hip/hip_runtime.h>

#define IGNORE_LABEL 255

constexpr int B      = 8;
constexpr int BANDS  = 31;
constexpr int H      = 512;
constexpr int W      = 512;
constexpr int NMAT   = 16;
constexpr int HW     = H * W;                 // 262144 (2^18)
constexpr long TOTAL_PIX = (long)B * HW;      // 2,097,152
constexpr long TOTAL_Q   = TOTAL_PIX / 4;     // 524,288 quads
constexpr int  NBLOCKS   = (int)(TOTAL_Q / 256);  // 2048 (exact)

typedef float  f32x4 __attribute__((ext_vector_type(4)));
typedef int    i32x4 __attribute__((ext_vector_type(4)));

// PPT=4 is the sweet spot: full 31-band unroll keeps ~31 in-flight dwordx4
// destinations + 8 accumulators within VGPR budget. PPT=8 (R3/R4) doubled
// live state -> spill/serialization, -30% regardless of address contiguity.
__global__ __launch_bounds__(256) void sad_main_kernel(
    const float* __restrict__ input,      // [B][BANDS][H][W]
    const int*   __restrict__ target,     // [B][1][H][W]
    const float* __restrict__ materials,  // [NMAT][BANDS]
    float*       __restrict__ part)       // [NBLOCKS]
{
    __shared__ float s_mat[NMAT][BANDS];
    __shared__ float s_tn2[NMAT];
    __shared__ float s_part[4];

    const int tid = threadIdx.x;

    // Addressing + target load issued BEFORE the staging barrier so the
    // 16B/lane target read overlaps materials staging.
    const long pix = ((long)blockIdx.x * blockDim.x + tid) * 4;
    const int  b   = (int)(pix >> 18);         // pix / HW (HW = 2^18)
    const int  off = (int)(pix & (HW - 1));

    const i32x4 code4 = __builtin_nontemporal_load(
        (const i32x4*)&target[(long)b * HW + off]);
    const float* ip = input + (long)b * BANDS * HW + off;

    // Stage materials into LDS (496 floats) + per-material ||t||^2.
    for (int i = tid; i < NMAT * BANDS; i += blockDim.x)
        s_mat[i / BANDS][i % BANDS] = materials[i];
    __syncthreads();
    if (tid < NMAT) {
        float s = 0.f;
        #pragma unroll
        for (int c = 0; c < BANDS; ++c) {
            float m = s_mat[tid][c];
            s = fmaf(m, m, s);
        }
        s_tn2[tid] = s;
    }
    __syncthreads();

    int codes[4] = { code4.x, code4.y, code4.z, code4.w };
    int safec[4];
    #pragma unroll
    for (int j = 0; j < 4; ++j) {
        int c = (codes[j] == IGNORE_LABEL) ? 0 : codes[j];
        safec[j] = (c < 0) ? 0 : ((c >= NMAT) ? 0 : c);  // memory-safety clamp
    }

    float dot[4] = {0.f, 0.f, 0.f, 0.f};
    float xn [4] = {0.f, 0.f, 0.f, 0.f};

    #pragma unroll
    for (int c = 0; c < BANDS; ++c) {
        const f32x4 v = __builtin_nontemporal_load((const f32x4*)&ip[(long)c * HW]);
        #pragma unroll
        for (int j = 0; j < 4; ++j) {
            const float m = s_mat[safec[j]][c];
            dot[j] = fmaf(v[j], m, dot[j]);
            xn [j] = fmaf(v[j], v[j], xn[j]);
        }
    }

    float acc = 0.f;
    #pragma unroll
    for (int j = 0; j < 4; ++j) {
        if (codes[j] != IGNORE_LABEL) {
            const float denom = sqrtf(xn[j] * s_tn2[safec[j]]);
            float cosv = dot[j] / denom;
            cosv = fminf(fmaxf(cosv, -1.f + 1e-7f), 1.f - 1e-7f);
            acc += acosf(cosv);
        }
    }

    // Wave-64 reduction, then per-block partial to workspace (no atomics).
    #pragma unroll
    for (int o = 32; o > 0; o >>= 1)
        acc += __shfl_down(acc, o, 64);

    const int wid = tid >> 6;
    if ((tid & 63) == 0) s_part[wid] = acc;
    __syncthreads();
    if (tid == 0)
        part[blockIdx.x] = s_part[0] + s_part[1] + s_part[2] + s_part[3];
}

__global__ __launch_bounds__(256) void sad_reduce_kernel(
    const float* __restrict__ part,  // [NBLOCKS]
    float*       __restrict__ out)   // [1]
{
    __shared__ float s_part[4];
    const int tid = threadIdx.x;

    float acc = 0.f;
    #pragma unroll
    for (int i = 0; i < NBLOCKS / 256; ++i)   // 8 each
        acc += part[i * 256 + tid];

    #pragma unroll
    for (int o = 32; o > 0; o >>= 1)
        acc += __shfl_down(acc, o, 64);

    const int wid = tid >> 6;
    if ((tid & 63) == 0) s_part[wid] = acc;
    __syncthreads();
    if (tid == 0)
        out[0] = s_part[0] + s_part[1] + s_part[2] + s_part[3];
}

extern "C" void kernel_launch(void* const* d_in, const int* in_sizes, int n_in,
                              void* d_out, int out_size, void* d_ws, size_t ws_size,
                              hipStream_t stream) {
    const float* input     = (const float*)d_in[0];
    const int*   target    = (const int*)  d_in[1];
    const float* materials = (const float*)d_in[2];
    float*       out       = (float*)d_out;
    float*       part      = (float*)d_ws;   // 2048 floats = 8 KB scratch

    sad_main_kernel<<<NBLOCKS, 256, 0, stream>>>(input, target, materials, part);
    sad_reduce_kernel<<<1, 256, 0, stream>>>(part, out);
}